// Round 7
// baseline (284.631 us; speedup 1.0000x reference)
//
#include <hip/hip_runtime.h>
#include <hip/hip_bf16.h>

typedef unsigned short u16;
typedef unsigned int u32;
typedef __attribute__((ext_vector_type(8))) short bf16x8;
typedef __attribute__((ext_vector_type(4))) float f32x4;

#define T_DIM 2048
#define B_DIM 32
#define H_DIM 512
#define M_DIM (T_DIM * B_DIM)

#define NCONV 4096            // blocks converting enc -> bf16 (staging order)
#define NR 512                // blocks computing r (one per h) + u
#define NW2 256               // blocks converting W2 -> fragment-major bf16

__device__ inline unsigned pack2(float a, float b) {
  union { __hip_bfloat162 h2; unsigned u; } c;
  c.h2 = __float22bfloat162_rn(make_float2(a, b));
  return c.u;
}

// Fused prep:
//  [0, NCONV): enc fp32 -> encbf bf16 in STAGING ORDER: chunk o (16B, 8 bf16) =
//     (mrow, gslot); holds enc[mrow][ (gslot^(mrow&7))*8 .. +8 ].  gemm's
//     global_load_lds then lands the XOR-swizzled tile in LDS with zero VALU.
//  [NCONV, NCONV+NR): h = bid-NCONV: r[b*512+h] = hidden[b]·W1[h] + b_attn[h]
//     (coalesced row-major W1 reads), and u[h] = W3[h]·W_cov (wave 0).
//  [NCONV+NR, +NW2): W2 -> bf16 fragment-major (1KB chunks = one wave B-frag).
__global__ __launch_bounds__(256) void prep_kernel(
    const float* __restrict__ hidden, const float* __restrict__ enc,
    const float* __restrict__ W_attn, const float* __restrict__ b_attn,
    const float* __restrict__ W_cov,
    u16* __restrict__ encbf, u16* __restrict__ W2bf,
    float* __restrict__ r, float* __restrict__ u)
{
  const int bid = blockIdx.x;
  const int t = threadIdx.x;

  if (bid < NCONV) {
    #pragma unroll
    for (int i = 0; i < 4; ++i) {
      int o = bid * 1024 + i * 256 + t;      // chunk index; wave spans one 2KB row
      int mrow = o >> 6;
      int gslot = o & 63;
      int gd = gslot ^ (mrow & 7);
      const float* src = enc + (size_t)mrow * 512 + gd * 8;
      float4 f0 = *(const float4*)src;
      float4 f1 = *(const float4*)(src + 4);
      uint4 p;
      p.x = pack2(f0.x, f0.y);
      p.y = pack2(f0.z, f0.w);
      p.z = pack2(f1.x, f1.y);
      p.w = pack2(f1.z, f1.w);
      *(uint4*)(encbf + (size_t)o * 8) = p;
    }
  } else if (bid < NCONV + NR) {
    const int h = bid - NCONV;
    const int bb = t >> 3, kq = t & 7;       // 32 b x 8 k-chunks of 64
    const float* w1 = W_attn + (size_t)h * 1536 + kq * 64;
    const float* hid = hidden + bb * 512 + kq * 64;
    float acc = 0.f;
    #pragma unroll
    for (int k = 0; k < 64; k += 4) {
      float4 x = *(const float4*)(hid + k);
      float4 ww = *(const float4*)(w1 + k);
      acc += x.x * ww.x + x.y * ww.y + x.z * ww.z + x.w * ww.w;
    }
    acc += __shfl_xor(acc, 1);
    acc += __shfl_xor(acc, 2);
    acc += __shfl_xor(acc, 4);
    if (kq == 0) r[bb * 512 + h] = acc + b_attn[h];
    if (t < 64) {
      const float* w3 = W_attn + (size_t)h * 1536 + 1024 + t * 8;
      const float* wc = W_cov + t * 8;
      float4 a0 = *(const float4*)w3, a1 = *(const float4*)(w3 + 4);
      float4 c0 = *(const float4*)wc, c1 = *(const float4*)(wc + 4);
      float su = a0.x * c0.x + a0.y * c0.y + a0.z * c0.z + a0.w * c0.w
               + a1.x * c1.x + a1.y * c1.y + a1.z * c1.z + a1.w * c1.w;
      #pragma unroll
      for (int o = 32; o; o >>= 1) su += __shfl_xor(su, o);
      if (t == 0) u[h] = su;
    }
  } else {
    const int tid = (bid - NCONV - NR) * 256 + t;   // 0..65535
    int j0 = tid * 4;
    int hh = j0 >> 9, kk = j0 & 511;
    float4 w = *(const float4*)(W_attn + (size_t)hh * 1536 + 512 + kk);
    uint2 p;
    p.x = pack2(w.x, w.y);
    p.y = pack2(w.z, w.w);
    int f = hh >> 4, c = hh & 15;
    int ks = kk >> 5, quad = (kk >> 3) & 3, e = kk & 7;   // e in {0,4}
    *(uint2*)(W2bf + (size_t)((f * 16 + ks) * 64 + quad * 16 + c) * 8 + e) = p;
  }
}

// m97-style GEMM. One block (512 thr, 8 waves) per 64-row m-tile. A-tile (64KB
// bf16, pre-swizzled) staged via 8 async global_load_lds (1KB each) per wave —
// whole tile in flight, zero staging VGPRs, zero cvt. One barrier. K-loop is
// barrier-free: wave owns a 64-wide n-slab; B frags are coalesced 1KB loads
// from fragment-major W2bf (L2-resident), parity double-buffered.
__global__ __launch_bounds__(512, 4) void gemm_score(
    const u16* __restrict__ encbf, const u16* __restrict__ W2bf,
    const float* __restrict__ r, const float* __restrict__ u,
    const float* __restrict__ vv, const float* __restrict__ cov,
    float* __restrict__ part)
{
  const int mt = blockIdx.x;
  const int m0 = mt * 64;
  const int tid = threadIdx.x;
  const int lane = tid & 63;
  const int w = tid >> 6;             // wave id 0..7 -> n-slab [w*64, w*64+64)
  const int quad = lane >> 4, col = lane & 15;

  __shared__ u16 As[64 * 512];        // 64 KB, staging order == swizzled [row][k]

  // ---- Stage: 8 async 1KB loads per wave; all 64KB in flight; one barrier. ----
  {
    const u16* g = encbf + ((size_t)mt * 4096 + w * 64 + lane) * 8;
    #pragma unroll
    for (int it = 0; it < 8; ++it) {
      __builtin_amdgcn_global_load_lds(
          (const __attribute__((address_space(1))) u32*)(g + (size_t)it * 512 * 8),
          (__attribute__((address_space(3))) u32*)(As + (it * 512 + w * 64) * 8),
          16, 0, 0);
    }
  }
  __syncthreads();

  // ---- K-loop, no barriers. B frags: coalesced 1KB loads, parity dbuf. ----
  f32x4 acc[4][4] = {};
  const u16* bbase = W2bf + (size_t)w * 32768 + lane * 8;

  bf16x8 bbuf[2][4];
  #pragma unroll
  for (int j = 0; j < 4; ++j)
    bbuf[0][j] = *(const bf16x8*)(bbase + j * 8192);

  #pragma unroll
  for (int ks = 0; ks < 16; ++ks) {
    if (ks < 15) {
      #pragma unroll
      for (int j = 0; j < 4; ++j)
        bbuf[(ks + 1) & 1][j] = *(const bf16x8*)(bbase + j * 8192 + (ks + 1) * 512);
    }
    #pragma unroll
    for (int i = 0; i < 4; ++i) {
      int row = i * 16 + col;
      bf16x8 af = *(const bf16x8*)&As[row * 512 + ((ks * 4 + quad) ^ (col & 7)) * 8];
      #pragma unroll
      for (int j = 0; j < 4; ++j)
        acc[i][j] = __builtin_amdgcn_mfma_f32_16x16x32_bf16(af, bbuf[ks & 1][j], acc[i][j], 0, 0, 0);
    }
  }

  // ---- Epilogue: e = relu(acc + r[b,h] + cov[b,t]*u[h]); partial = e·v over wave's 64 h ----
  float uj[4], vj[4];
  #pragma unroll
  for (int j = 0; j < 4; ++j) {
    int gh = w * 64 + j * 16 + col;
    uj[j] = u[gh];
    vj[j] = vv[gh];
  }
  #pragma unroll
  for (int pr = 0; pr < 2; ++pr) {
    #pragma unroll
    for (int reg = 0; reg < 4; ++reg) {
      int b = pr * 16 + quad * 4 + reg;         // = m & 31 (m0 % 64 == 0)
      const float* rb = r + b * 512;
      float rbj[4];
      #pragma unroll
      for (int j = 0; j < 4; ++j) rbj[j] = rb[w * 64 + j * 16 + col];
      #pragma unroll
      for (int isub = 0; isub < 2; ++isub) {
        int i = pr + isub * 2;
        int t = (m0 >> 5) + isub;
        float cv = cov[b * 2048 + t];
        float s = 0.f;
        #pragma unroll
        for (int j = 0; j < 4; ++j) {
          float e = acc[i][j][reg] + rbj[j] + cv * uj[j];
          e = fmaxf(e, 0.f);
          s += e * vj[j];
        }
        s += __shfl_xor(s, 1);
        s += __shfl_xor(s, 2);
        s += __shfl_xor(s, 4);
        s += __shfl_xor(s, 8);
        if (col == 0) part[(size_t)(w * 32 + b) * 2048 + t] = s;
      }
    }
  }
}

// Softmax over T per batch + coverage update. 32 blocks x 256 threads. part layout [p][b][t].
__global__ __launch_bounds__(256) void softmax_kernel(
    const float* __restrict__ part, const float* __restrict__ cov, float* __restrict__ out)
{
  const int b = blockIdx.x;
  const int tid = threadIdx.x;
  const int lane = tid & 63, wid = tid >> 6;
  __shared__ float red[4];
  float loc[8];
  float lmax = -3.4e38f;
  #pragma unroll
  for (int i = 0; i < 8; ++i) {
    int t = tid + i * 256;
    float s = 0.f;
    #pragma unroll
    for (int p = 0; p < 8; ++p) s += part[(size_t)(p * 32 + b) * 2048 + t];
    loc[i] = s;
    lmax = fmaxf(lmax, s);
  }
  #pragma unroll
  for (int o = 32; o; o >>= 1) lmax = fmaxf(lmax, __shfl_xor(lmax, o));
  if (lane == 0) red[wid] = lmax;
  __syncthreads();
  float bmax = fmaxf(fmaxf(red[0], red[1]), fmaxf(red[2], red[3]));
  __syncthreads();
  float lsum = 0.f;
  #pragma unroll
  for (int i = 0; i < 8; ++i) { loc[i] = __expf(loc[i] - bmax); lsum += loc[i]; }
  #pragma unroll
  for (int o = 32; o; o >>= 1) lsum += __shfl_xor(lsum, o);
  if (lane == 0) red[wid] = lsum;
  __syncthreads();
  float inv = 1.0f / (red[0] + red[1] + red[2] + red[3]);
  #pragma unroll
  for (int i = 0; i < 8; ++i) {
    int t = tid + i * 256;
    float a = loc[i] * inv;
    out[b * 2048 + t] = a;                               // attn_weights [B,1,T]
    out[65536 + b * 2048 + t] = cov[b * 2048 + t] + a;   // coverage_new [B,T]
  }
}

extern "C" void kernel_launch(void* const* d_in, const int* in_sizes, int n_in,
                              void* d_out, int out_size, void* d_ws, size_t ws_size,
                              hipStream_t stream) {
  const float* hidden = (const float*)d_in[0];   // [1,B,H]
  const float* enc    = (const float*)d_in[1];   // [T,B,H]
  const float* cov    = (const float*)d_in[2];   // [B,T]
  const float* W_attn = (const float*)d_in[3];   // [H,3H]
  const float* b_attn = (const float*)d_in[4];   // [H]
  const float* vv     = (const float*)d_in[5];   // [H]
  const float* W_cov  = (const float*)d_in[6];   // [H,1]
  float* out = (float*)d_out;

  u16* encbf = (u16*)d_ws;                                   // 64 MiB (staging order)
  u16* W2bf  = (u16*)((char*)d_ws + (size_t)67108864);       // 512 KB (fragment-major)
  float* r   = (float*)((char*)d_ws + 67108864 + 524288);    // 64 KB
  float* u   = r + 32 * 512;                                 // 2 KB
  float* part = u + 512;                                     // 2 MB

  hipLaunchKernelGGL(prep_kernel, dim3(NCONV + NR + NW2), dim3(256), 0, stream,
                     hidden, enc, W_attn, b_attn, W_cov, encbf, W2bf, r, u);
  hipLaunchKernelGGL(gemm_score, dim3(1024), dim3(512), 0, stream,
                     encbf, W2bf, r, u, vv, cov, part);
  hipLaunchKernelGGL(softmax_kernel, dim3(32), dim3(256), 0, stream,
                     part, cov, out);
}